// Round 7
// baseline (495.235 us; speedup 1.0000x reference)
//
#include <hip/hip_runtime.h>
#include <hip/hip_bf16.h>
#include <math.h>

#define IN_DIM 128
#define OUT_DIM 64
#define NEG_SLOPE 0.01f
#define BCAP 4096          // slots per 128-node bucket (avg fill ~2046, ~45 sigma margin)
#define EPT 16             // edges per thread in part1 half (4096 edges/block)

typedef __attribute__((ext_vector_type(8))) short bf8_t;   // 8 bf16 (4 VGPRs)
typedef __attribute__((ext_vector_type(4))) float f4_t;    // MFMA acc

__device__ __forceinline__ bf8_t pack8(float4 a, float4 b) {
    union { bf8_t v; __hip_bfloat162 h[4]; } u;
    u.h[0] = __float22bfloat162_rn(make_float2(a.x, a.y));
    u.h[1] = __float22bfloat162_rn(make_float2(a.z, a.w));
    u.h[2] = __float22bfloat162_rn(make_float2(b.x, b.y));
    u.h[3] = __float22bfloat162_rn(make_float2(b.z, b.w));
    return u.v;
}

// ---- K_front: blocks [0,NP1) = part1 (bin edges), blocks [NP1,..) = MFMA gemm ----
// part1 payload u32 = (bucket<<23) | (src<<7) | (dst&127), bucket = dst>>7 (< 512).
__global__ __launch_bounds__(256) void k_front(
    // part1 args
    const int* __restrict__ src, const int* __restrict__ dst,
    int* __restrict__ bucket_cursor, unsigned* __restrict__ tmp, int E,
    // gemm args
    const float4* __restrict__ h4, const float4* __restrict__ W4,
    const float* __restrict__ Wattn,
    __hip_bfloat16* __restrict__ zb, float* __restrict__ s_l, float* __restrict__ s_r,
    int N, int NP1)
{
    __shared__ int cnt[512];
    __shared__ int cur[512];

    if (blockIdx.x < NP1) {
        // ================= part1: bin 4096 edges into buckets =================
        const int t = threadIdx.x;
        const int base_e = blockIdx.x * (256 * EPT);

        cnt[t] = 0; cnt[t + 256] = 0;
        __syncthreads();

        unsigned pArr[EPT];
        #pragma unroll
        for (int i = 0; i < EPT; i++) {
            int ei = base_e + i * 256 + t;
            if (ei < E) {
                int s = src[ei], d = dst[ei];
                int b = d >> 7;
                pArr[i] = ((unsigned)b << 23) | ((unsigned)s << 7) | (unsigned)(d & 127);
                atomicAdd(&cnt[b], 1);
            } else {
                pArr[i] = 0xFFFFFFFFu;
            }
        }
        __syncthreads();

        for (int b = t; b < 512; b += 256)
            if (cnt[b] > 0)
                cur[b] = atomicAdd(&bucket_cursor[b], cnt[b]);
        __syncthreads();

        #pragma unroll
        for (int i = 0; i < EPT; i++) {
            unsigned p = pArr[i];
            if (p == 0xFFFFFFFFu) continue;
            int b = p >> 23;
            int slot = atomicAdd(&cur[b], 1);
            tmp[(size_t)b * BCAP + slot] = p;
        }
    } else {
        // ================= gemm: MFMA, 64 nodes per block =================
        const int lane = threadIdx.x & 63;
        const int wv   = threadIdx.x >> 6;
        const int col  = lane & 15, quad = lane >> 4;
        const int n0   = (blockIdx.x - NP1) * 64 + wv * 16;
        if (n0 >= N) return;

        bf8_t bf[4][4];
        #pragma unroll
        for (int ns = 0; ns < 4; ns++) {
            const float4* wrow = W4 + (size_t)(ns * 16 + col) * (IN_DIM / 4);
            #pragma unroll
            for (int kb = 0; kb < 4; kb++) {
                float4 x = wrow[kb * 8 + quad * 2];
                float4 y = wrow[kb * 8 + quad * 2 + 1];
                bf[kb][ns] = pack8(x, y);
            }
        }

        const int  na = n0 + col;
        const bool nv = (na < N);
        const float4* hrow = h4 + (size_t)(nv ? na : 0) * (IN_DIM / 4);
        const float4 zero = make_float4(0.f, 0.f, 0.f, 0.f);

        f4_t acc[4];
        #pragma unroll
        for (int ns = 0; ns < 4; ns++) acc[ns] = (f4_t){0.f, 0.f, 0.f, 0.f};

        #pragma unroll
        for (int kb = 0; kb < 4; kb++) {
            float4 x = nv ? hrow[kb * 8 + quad * 2]     : zero;
            float4 y = nv ? hrow[kb * 8 + quad * 2 + 1] : zero;
            bf8_t a = pack8(x, y);
            #pragma unroll
            for (int ns = 0; ns < 4; ns++)
                acc[ns] = __builtin_amdgcn_mfma_f32_16x16x32_bf16(a, bf[kb][ns], acc[ns], 0, 0, 0);
        }

        float alv[4], arv[4];
        #pragma unroll
        for (int ns = 0; ns < 4; ns++) {
            alv[ns] = Wattn[ns * 16 + col];
            arv[ns] = Wattn[OUT_DIM + ns * 16 + col];
        }
        #pragma unroll
        for (int r = 0; r < 4; r++) {
            const int nn = n0 + quad * 4 + r;
            float pl = acc[0][r] * alv[0] + acc[1][r] * alv[1] + acc[2][r] * alv[2] + acc[3][r] * alv[3];
            float pr = acc[0][r] * arv[0] + acc[1][r] * arv[1] + acc[2][r] * arv[2] + acc[3][r] * arv[3];
            #pragma unroll
            for (int o = 1; o < 16; o <<= 1) {
                pl += __shfl_xor(pl, o, 64);
                pr += __shfl_xor(pr, o, 64);
            }
            if (nn < N) {
                __hip_bfloat16* zr = zb + (size_t)nn * OUT_DIM;
                #pragma unroll
                for (int ns = 0; ns < 4; ns++)
                    zr[ns * 16 + col] = __float2bfloat16(acc[ns][r]);
                if (col == 0) { s_l[nn] = pl; s_r[nn] = pr; }
            }
        }
    }
}

// ---- K_bucket: one block per 128-node bucket; LDS accumulator, no CSR ----
// 512 threads = 8 waves. acc[128][64] fp32 in LDS; denominators via ds atomics.
__global__ __launch_bounds__(512) void k_bucket(
    const unsigned* __restrict__ tmp, const int* __restrict__ bucket_cnt,
    const float* __restrict__ s_l, const float* __restrict__ s_r,
    const unsigned short* __restrict__ zb16,
    float4* __restrict__ out4, int N)
{
    __shared__ float acc_s[128 * 64];   // 32 KB
    __shared__ float den_s[128];
    __shared__ float srs[128];

    const int b = blockIdx.x, t = threadIdx.x;
    const int lane = t & 63, wv = t >> 6;
    const int mb = bucket_cnt[b];
    const int nbase = b * 128;

    for (int i = t; i < 128 * 16; i += 512)
        ((float4*)acc_s)[i] = make_float4(0.f, 0.f, 0.f, 0.f);
    if (t < 128) {
        int n = nbase + t;
        den_s[t] = 0.f;
        srs[t] = (n < N) ? s_r[n] : 0.f;
    }
    __syncthreads();

    const unsigned* mybuf = tmp + (size_t)b * BCAP;
    for (int base = wv * 64; base < mb; base += 512) {
        int i = base + lane;
        bool valid = (i < mb);
        unsigned p = valid ? mybuf[i] : 0u;
        int s_my = (p >> 7) & 0xFFFFu;
        float ex_my = 0.f;
        if (valid) {
            int dlow = p & 127u;
            float e = s_l[s_my] + srs[dlow];
            e = (e > 0.f) ? e : NEG_SLOPE * e;
            ex_my = __expf(e);
            atomicAdd(&den_s[dlow], ex_my);
        }
        int cnt = mb - base; if (cnt > 64) cnt = 64;
        for (int j = 0; j < cnt; ++j) {
            unsigned pj = __shfl(p, j, 64);
            float ex = __shfl(ex_my, j, 64);
            int d = pj & 127u;
            int s = (pj >> 7) & 0xFFFFu;
            float zv = __uint_as_float((unsigned)zb16[(size_t)s * 64 + lane] << 16);
            atomicAdd(&acc_s[d * 64 + lane], ex * zv);   // 2-way bank alias: free
        }
    }
    __syncthreads();

    // write out: 128 nodes x 16 float4, normalized
    for (int i = t; i < 128 * 16; i += 512) {
        int nl = i >> 4;
        int n = nbase + nl;
        if (n < N) {
            float den = den_s[nl];
            float inv = (den > 0.f) ? 1.f / den : 0.f;
            float4 v = ((float4*)acc_s)[i];
            out4[(size_t)n * 16 + (i & 15)] =
                make_float4(v.x * inv, v.y * inv, v.z * inv, v.w * inv);
        }
    }
}

extern "C" void kernel_launch(void* const* d_in, const int* in_sizes, int n_in,
                              void* d_out, int out_size, void* d_ws, size_t ws_size,
                              hipStream_t stream)
{
    const float* h     = (const float*)d_in[0];
    const float* Wfc   = (const float*)d_in[1];
    const float* Wattn = (const float*)d_in[2];
    const int*   src   = (const int*)d_in[3];
    const int*   dst   = (const int*)d_in[4];
    const int N = in_sizes[0] / IN_DIM;
    const int E = in_sizes[3];
    const int NBK = (N + 127) / 128;                    // 391 buckets
    const int NP1 = (E + 256 * EPT - 1) / (256 * EPT);  // 196 part1 blocks

    // ws layout: z_bf16[N*64] | s_l[N] | s_r[N] | bucket_cursor[512] | tmp[NBK*BCAP] (u32)
    __hip_bfloat16* zb = (__hip_bfloat16*)d_ws;
    float* s_l     = (float*)(zb + (size_t)N * OUT_DIM);
    float* s_r     = s_l + N;
    int*   bcursor = (int*)(s_r + N);
    unsigned* tmp  = (unsigned*)(bcursor + 512);

    const int nblk_g = (N + 63) / 64;                   // 782 gemm blocks

    hipMemsetAsync(bcursor, 0, 512 * sizeof(int), stream);

    k_front <<<NP1 + nblk_g, 256, 0, stream>>>(src, dst, bcursor, tmp, E,
                                               (const float4*)h, (const float4*)Wfc, Wattn,
                                               zb, s_l, s_r, N, NP1);
    k_bucket<<<NBK, 512, 0, stream>>>(tmp, bcursor, s_l, s_r,
                                      (const unsigned short*)zb, (float4*)d_out, N);
}

// Round 8
// 156.937 us; speedup vs baseline: 3.1556x; 3.1556x over previous
//
#include <hip/hip_runtime.h>
#include <hip/hip_bf16.h>
#include <math.h>

#define IN_DIM 128
#define OUT_DIM 64
#define NEG_SLOPE 0.01f
#define BCAP 2048          // slots per 64-node bucket (avg fill ~1023, +32 sigma margin)
#define EPT 16             // edges per thread in part1 (4096 edges/block)

typedef __attribute__((ext_vector_type(8))) short bf8_t;   // 8 bf16 (4 VGPRs)
typedef __attribute__((ext_vector_type(4))) float f4_t;    // MFMA acc

__device__ __forceinline__ bf8_t pack8(float4 a, float4 b) {
    union { bf8_t v; __hip_bfloat162 h[4]; } u;
    u.h[0] = __float22bfloat162_rn(make_float2(a.x, a.y));
    u.h[1] = __float22bfloat162_rn(make_float2(a.z, a.w));
    u.h[2] = __float22bfloat162_rn(make_float2(b.x, b.y));
    u.h[3] = __float22bfloat162_rn(make_float2(b.z, b.w));
    return u.v;
}

// ---- K_front: blocks [0,NP1) = part1 (bin edges), blocks [NP1,..) = MFMA gemm ----
// payload u32 = (bucket<<22) | (src<<6) | (dst&63), bucket = dst>>6 (< 1024).
__global__ __launch_bounds__(256) void k_front(
    const int* __restrict__ src, const int* __restrict__ dst,
    int* __restrict__ bucket_cursor, unsigned* __restrict__ tmp, int E,
    const float4* __restrict__ h4, const float4* __restrict__ W4,
    const float* __restrict__ Wattn,
    __hip_bfloat16* __restrict__ zb, float* __restrict__ s_l, float* __restrict__ s_r,
    int N, int NP1)
{
    __shared__ int cnt[1024];
    __shared__ int cur[1024];

    if (blockIdx.x < NP1) {
        // ================= part1: bin 4096 edges into buckets =================
        const int t = threadIdx.x;
        const int base_e = blockIdx.x * (256 * EPT);

        for (int b = t; b < 1024; b += 256) cnt[b] = 0;
        __syncthreads();

        unsigned pArr[EPT];
        #pragma unroll
        for (int i = 0; i < EPT; i++) {
            int ei = base_e + i * 256 + t;
            if (ei < E) {
                int s = src[ei], d = dst[ei];
                int b = d >> 6;
                pArr[i] = ((unsigned)b << 22) | ((unsigned)s << 6) | (unsigned)(d & 63);
                atomicAdd(&cnt[b], 1);
            } else {
                pArr[i] = 0xFFFFFFFFu;
            }
        }
        __syncthreads();

        for (int b = t; b < 1024; b += 256)
            if (cnt[b] > 0)
                cur[b] = atomicAdd(&bucket_cursor[b], cnt[b]);
        __syncthreads();

        #pragma unroll
        for (int i = 0; i < EPT; i++) {
            unsigned p = pArr[i];
            if (p == 0xFFFFFFFFu) continue;
            int b = p >> 22;
            int slot = atomicAdd(&cur[b], 1);
            if (slot < BCAP)
                tmp[(size_t)b * BCAP + slot] = p;
        }
    } else {
        // ================= gemm: MFMA, 64 nodes per block =================
        const int lane = threadIdx.x & 63;
        const int wv   = threadIdx.x >> 6;
        const int col  = lane & 15, quad = lane >> 4;
        const int n0   = (blockIdx.x - NP1) * 64 + wv * 16;
        if (n0 >= N) return;

        bf8_t bf[4][4];
        #pragma unroll
        for (int ns = 0; ns < 4; ns++) {
            const float4* wrow = W4 + (size_t)(ns * 16 + col) * (IN_DIM / 4);
            #pragma unroll
            for (int kb = 0; kb < 4; kb++) {
                float4 x = wrow[kb * 8 + quad * 2];
                float4 y = wrow[kb * 8 + quad * 2 + 1];
                bf[kb][ns] = pack8(x, y);
            }
        }

        const int  na = n0 + col;
        const bool nv = (na < N);
        const float4* hrow = h4 + (size_t)(nv ? na : 0) * (IN_DIM / 4);
        const float4 zero = make_float4(0.f, 0.f, 0.f, 0.f);

        f4_t acc[4];
        #pragma unroll
        for (int ns = 0; ns < 4; ns++) acc[ns] = (f4_t){0.f, 0.f, 0.f, 0.f};

        #pragma unroll
        for (int kb = 0; kb < 4; kb++) {
            float4 x = nv ? hrow[kb * 8 + quad * 2]     : zero;
            float4 y = nv ? hrow[kb * 8 + quad * 2 + 1] : zero;
            bf8_t a = pack8(x, y);
            #pragma unroll
            for (int ns = 0; ns < 4; ns++)
                acc[ns] = __builtin_amdgcn_mfma_f32_16x16x32_bf16(a, bf[kb][ns], acc[ns], 0, 0, 0);
        }

        float alv[4], arv[4];
        #pragma unroll
        for (int ns = 0; ns < 4; ns++) {
            alv[ns] = Wattn[ns * 16 + col];
            arv[ns] = Wattn[OUT_DIM + ns * 16 + col];
        }
        #pragma unroll
        for (int r = 0; r < 4; r++) {
            const int nn = n0 + quad * 4 + r;
            float pl = acc[0][r] * alv[0] + acc[1][r] * alv[1] + acc[2][r] * alv[2] + acc[3][r] * alv[3];
            float pr = acc[0][r] * arv[0] + acc[1][r] * arv[1] + acc[2][r] * arv[2] + acc[3][r] * arv[3];
            #pragma unroll
            for (int o = 1; o < 16; o <<= 1) {
                pl += __shfl_xor(pl, o, 64);
                pr += __shfl_xor(pr, o, 64);
            }
            if (nn < N) {
                __hip_bfloat16* zr = zb + (size_t)nn * OUT_DIM;
                #pragma unroll
                for (int ns = 0; ns < 4; ns++)
                    zr[ns * 16 + col] = __float2bfloat16(acc[ns][r]);
                if (col == 0) { s_l[nn] = pl; s_r[nn] = pr; }
            }
        }
    }
}

// ---- K_tail: one block per 64-node bucket. LDS counting sort (u16 src list),
// then per-node wave aggregation with register accumulators (R5-proven loop).
__global__ __launch_bounds__(256) void k_tail(
    const unsigned* __restrict__ tmp, const int* __restrict__ bucket_cnt,
    const float* __restrict__ s_l, const float* __restrict__ s_r,
    const uint2* __restrict__ zb2, float4* __restrict__ out4, int N)
{
    __shared__ unsigned short sedge[BCAP];   // 4 KB
    __shared__ int cnt_s[64], off_s[64], cur_s[64];
    __shared__ float srs[64];

    const int b = blockIdx.x, t = threadIdx.x;
    const int lane = t & 63, wv = t >> 6;
    const int nbase = b * 64;
    int mb = bucket_cnt[b];
    if (mb > BCAP) mb = BCAP;

    if (t < 64) {
        cnt_s[t] = 0;
        int n = nbase + t;
        srs[t] = (n < N) ? s_r[n] : 0.f;
    }
    __syncthreads();

    const unsigned* mybuf = tmp + (size_t)b * BCAP;
    unsigned pl[BCAP / 256];     // 8 payloads max per thread
    int ne = 0;
    for (int i = t; i < mb; i += 256) {
        unsigned p = mybuf[i];
        pl[ne++] = p;
        atomicAdd(&cnt_s[p & 63u], 1);
    }
    __syncthreads();

    // exclusive scan of cnt_s[64] by wave 0 (shfl, no barriers inside)
    if (t < 64) {
        int c = cnt_s[t];
        int inc = c;
        #pragma unroll
        for (int o = 1; o < 64; o <<= 1) {
            int v = __shfl_up(inc, o, 64);
            if (lane >= o) inc += v;
        }
        off_s[t] = inc - c;
        cur_s[t] = inc - c;
    }
    __syncthreads();

    for (int i = 0; i < ne; i++) {
        unsigned p = pl[i];
        int d = p & 63u;
        int slot = atomicAdd(&cur_s[d], 1);
        sedge[slot] = (unsigned short)((p >> 6) & 0xFFFFu);
    }
    __syncthreads();

    // ---- phase 2: per-node wave processing ----
    const int c4 = lane & 15;
    const int g  = lane >> 4;
    const float4 zero = make_float4(0.f, 0.f, 0.f, 0.f);

    for (int nl = wv; nl < 64; nl += 4) {
        const int n = nbase + nl;
        if (n >= N) continue;
        const int beg = off_s[nl];
        const int deg = cnt_s[nl] - beg;     // cur_s ended at off+cnt; cnt_s holds count
        // NOTE: cnt_s[nl] is the original count (cur_s was the cursor) — recompute:
        const int deg2 = cur_s[nl] - beg;
        const int end = beg + deg2;
        float4* op = out4 + (size_t)n * 16;

        if (deg2 <= 0) {
            if (lane < 16) op[lane] = zero;
            continue;
        }

        const float sr = srs[nl];
        float4 acc = zero;
        float dsum = 0.f;

        for (int cs = beg; cs < end; cs += 64) {
            int i = cs + lane;
            int s_my = 0; float ex_my = 0.f;
            if (i < end) {
                s_my = sedge[i];
                float e = s_l[s_my] + sr;
                e = (e > 0.f) ? e : NEG_SLOPE * e;
                ex_my = __expf(e);
            }
            dsum += ex_my;
            int c = end - cs; if (c > 64) c = 64;
            for (int j = 0; j < c; j += 4) {
                int jj = j + g;
                int   s  = __shfl(s_my, jj & 63, 64);
                float ex = __shfl(ex_my, jj & 63, 64);
                if (jj >= c) ex = 0.f;
                union { uint2 u; __hip_bfloat162 h[2]; } zu;
                zu.u = zb2[(size_t)s * 16 + c4];
                float2 f0 = __bfloat1622float2(zu.h[0]);
                float2 f1 = __bfloat1622float2(zu.h[1]);
                acc.x += ex * f0.x; acc.y += ex * f0.y;
                acc.z += ex * f1.x; acc.w += ex * f1.y;
            }
        }

        #pragma unroll
        for (int off = 16; off <= 32; off <<= 1) {
            acc.x += __shfl_xor(acc.x, off, 64);
            acc.y += __shfl_xor(acc.y, off, 64);
            acc.z += __shfl_xor(acc.z, off, 64);
            acc.w += __shfl_xor(acc.w, off, 64);
        }
        #pragma unroll
        for (int off = 32; off; off >>= 1) dsum += __shfl_xor(dsum, off, 64);

        if (lane < 16) {
            float inv = 1.f / dsum;
            op[c4] = make_float4(acc.x * inv, acc.y * inv, acc.z * inv, acc.w * inv);
        }
    }
}

extern "C" void kernel_launch(void* const* d_in, const int* in_sizes, int n_in,
                              void* d_out, int out_size, void* d_ws, size_t ws_size,
                              hipStream_t stream)
{
    const float* h     = (const float*)d_in[0];
    const float* Wfc   = (const float*)d_in[1];
    const float* Wattn = (const float*)d_in[2];
    const int*   src   = (const int*)d_in[3];
    const int*   dst   = (const int*)d_in[4];
    const int N = in_sizes[0] / IN_DIM;
    const int E = in_sizes[3];
    const int NBK = (N + 63) / 64;                      // 782 buckets
    const int NP1 = (E + 256 * EPT - 1) / (256 * EPT);  // 196 part1 blocks

    // ws layout: z_bf16[N*64] | s_l[N] | s_r[N] | bucket_cursor[1024] | tmp[NBK*BCAP]
    __hip_bfloat16* zb = (__hip_bfloat16*)d_ws;
    float* s_l     = (float*)(zb + (size_t)N * OUT_DIM);
    float* s_r     = s_l + N;
    int*   bcursor = (int*)(s_r + N);
    unsigned* tmp  = (unsigned*)(bcursor + 1024);

    const int nblk_g = (N + 63) / 64;                   // 782 gemm blocks

    hipMemsetAsync(bcursor, 0, 1024 * sizeof(int), stream);

    k_front<<<NP1 + nblk_g, 256, 0, stream>>>(src, dst, bcursor, tmp, E,
                                              (const float4*)h, (const float4*)Wfc, Wattn,
                                              zb, s_l, s_r, N, NP1);
    k_tail <<<NBK, 256, 0, stream>>>(tmp, bcursor, s_l, s_r,
                                     (const uint2*)zb, (float4*)d_out, N);
}

// Round 9
// 142.928 us; speedup vs baseline: 3.4649x; 1.0980x over previous
//
#include <hip/hip_runtime.h>
#include <hip/hip_bf16.h>
#include <math.h>

#define IN_DIM 128
#define OUT_DIM 64
#define NEG_SLOPE 0.01f
#define BCAP 2048          // slots per 64-node bucket (avg fill ~1023)
#define EPT 16             // edges per thread in part1 (4096 edges/block)

typedef __attribute__((ext_vector_type(8))) short bf8_t;   // 8 bf16 (4 VGPRs)
typedef __attribute__((ext_vector_type(4))) float f4_t;    // MFMA acc

__device__ __forceinline__ bf8_t pack8(float4 a, float4 b) {
    union { bf8_t v; __hip_bfloat162 h[4]; } u;
    u.h[0] = __float22bfloat162_rn(make_float2(a.x, a.y));
    u.h[1] = __float22bfloat162_rn(make_float2(a.z, a.w));
    u.h[2] = __float22bfloat162_rn(make_float2(b.x, b.y));
    u.h[3] = __float22bfloat162_rn(make_float2(b.z, b.w));
    return u.v;
}

// ---- K_front: blocks [0,NP1) = part1 (bin edges), blocks [NP1,..) = MFMA gemm ----
// payload u32 = (bucket<<22) | (src<<6) | (dst&63), bucket = dst>>6 (< 1024).
__global__ __launch_bounds__(256) void k_front(
    const int* __restrict__ src, const int* __restrict__ dst,
    int* __restrict__ bucket_cursor, unsigned* __restrict__ tmp, int E,
    const float4* __restrict__ h4, const float4* __restrict__ W4,
    const float* __restrict__ Wattn,
    __hip_bfloat16* __restrict__ zb, float* __restrict__ s_l, float* __restrict__ s_r,
    int N, int NP1)
{
    __shared__ int cnt[1024];
    __shared__ int cur[1024];

    if (blockIdx.x < NP1) {
        // ================= part1: bin 4096 edges into buckets =================
        const int t = threadIdx.x;
        const int base_e = blockIdx.x * (256 * EPT);

        for (int b = t; b < 1024; b += 256) cnt[b] = 0;
        __syncthreads();

        unsigned pArr[EPT];
        #pragma unroll
        for (int i = 0; i < EPT; i++) {
            int ei = base_e + i * 256 + t;
            if (ei < E) {
                int s = src[ei], d = dst[ei];
                int b = d >> 6;
                pArr[i] = ((unsigned)b << 22) | ((unsigned)s << 6) | (unsigned)(d & 63);
                atomicAdd(&cnt[b], 1);
            } else {
                pArr[i] = 0xFFFFFFFFu;
            }
        }
        __syncthreads();

        for (int b = t; b < 1024; b += 256)
            if (cnt[b] > 0)
                cur[b] = atomicAdd(&bucket_cursor[b], cnt[b]);
        __syncthreads();

        #pragma unroll
        for (int i = 0; i < EPT; i++) {
            unsigned p = pArr[i];
            if (p == 0xFFFFFFFFu) continue;
            int b = p >> 22;
            int slot = atomicAdd(&cur[b], 1);
            if (slot < BCAP)
                tmp[(size_t)b * BCAP + slot] = p;
        }
    } else {
        // ================= gemm: MFMA, 64 nodes per block =================
        const int lane = threadIdx.x & 63;
        const int wv   = threadIdx.x >> 6;
        const int col  = lane & 15, quad = lane >> 4;
        const int n0   = (blockIdx.x - NP1) * 64 + wv * 16;
        if (n0 >= N) return;

        bf8_t bf[4][4];
        #pragma unroll
        for (int ns = 0; ns < 4; ns++) {
            const float4* wrow = W4 + (size_t)(ns * 16 + col) * (IN_DIM / 4);
            #pragma unroll
            for (int kb = 0; kb < 4; kb++) {
                float4 x = wrow[kb * 8 + quad * 2];
                float4 y = wrow[kb * 8 + quad * 2 + 1];
                bf[kb][ns] = pack8(x, y);
            }
        }

        const int  na = n0 + col;
        const bool nv = (na < N);
        const float4* hrow = h4 + (size_t)(nv ? na : 0) * (IN_DIM / 4);
        const float4 zero = make_float4(0.f, 0.f, 0.f, 0.f);

        f4_t acc[4];
        #pragma unroll
        for (int ns = 0; ns < 4; ns++) acc[ns] = (f4_t){0.f, 0.f, 0.f, 0.f};

        #pragma unroll
        for (int kb = 0; kb < 4; kb++) {
            float4 x = nv ? hrow[kb * 8 + quad * 2]     : zero;
            float4 y = nv ? hrow[kb * 8 + quad * 2 + 1] : zero;
            bf8_t a = pack8(x, y);
            #pragma unroll
            for (int ns = 0; ns < 4; ns++)
                acc[ns] = __builtin_amdgcn_mfma_f32_16x16x32_bf16(a, bf[kb][ns], acc[ns], 0, 0, 0);
        }

        float alv[4], arv[4];
        #pragma unroll
        for (int ns = 0; ns < 4; ns++) {
            alv[ns] = Wattn[ns * 16 + col];
            arv[ns] = Wattn[OUT_DIM + ns * 16 + col];
        }
        #pragma unroll
        for (int r = 0; r < 4; r++) {
            const int nn = n0 + quad * 4 + r;
            float pl = acc[0][r] * alv[0] + acc[1][r] * alv[1] + acc[2][r] * alv[2] + acc[3][r] * alv[3];
            float pr = acc[0][r] * arv[0] + acc[1][r] * arv[1] + acc[2][r] * arv[2] + acc[3][r] * arv[3];
            #pragma unroll
            for (int o = 1; o < 16; o <<= 1) {
                pl += __shfl_xor(pl, o, 64);
                pr += __shfl_xor(pr, o, 64);
            }
            if (nn < N) {
                __hip_bfloat16* zr = zb + (size_t)nn * OUT_DIM;
                #pragma unroll
                for (int ns = 0; ns < 4; ns++)
                    zr[ns * 16 + col] = __float2bfloat16(acc[ns][r]);
                if (col == 0) { s_l[nn] = pl; s_r[nn] = pr; }
            }
        }
    }
}

// ---- K_tail: one block per 64-node bucket.
// Phase 1: LDS counting sort; compute ex + denominators during scatter.
// Phase 2: one 8-lane group per node — NO shfl, 8 edges' rows in flight/blockwave.
__global__ __launch_bounds__(256) void k_tail(
    const unsigned* __restrict__ tmp, const int* __restrict__ bucket_cnt,
    const float* __restrict__ s_l, const float* __restrict__ s_r,
    const uint4* __restrict__ zb4, float4* __restrict__ out4, int N)
{
    __shared__ unsigned short sedge[BCAP];   // 4 KB
    __shared__ float sex[BCAP];              // 8 KB
    __shared__ int cnt_s[64], off_s[64], cur_s[64];
    __shared__ float den_s[64], srs[64];

    const int b = blockIdx.x, t = threadIdx.x;
    const int lane = t & 63;
    const int nbase = b * 64;
    int mb = bucket_cnt[b];
    if (mb > BCAP) mb = BCAP;

    if (t < 64) {
        cnt_s[t] = 0;
        den_s[t] = 0.f;
        int n = nbase + t;
        srs[t] = (n < N) ? s_r[n] : 0.f;
    }
    __syncthreads();

    const unsigned* mybuf = tmp + (size_t)b * BCAP;
    unsigned pl[BCAP / 256];     // <= 8 payloads per thread
    int ne = 0;
    for (int i = t; i < mb; i += 256) {
        unsigned p = mybuf[i];
        pl[ne++] = p;
        atomicAdd(&cnt_s[p & 63u], 1);
    }
    __syncthreads();

    // exclusive scan of cnt_s[64] by wave 0 (shfl only)
    if (t < 64) {
        int c = cnt_s[t];
        int inc = c;
        #pragma unroll
        for (int o = 1; o < 64; o <<= 1) {
            int v = __shfl_up(inc, o, 64);
            if (lane >= o) inc += v;
        }
        off_s[t] = inc - c;
        cur_s[t] = inc - c;
    }
    __syncthreads();

    // scatter + compute ex + accumulate denominators
    for (int i = 0; i < ne; i++) {
        unsigned p = pl[i];
        int d = p & 63u;
        int s = (p >> 6) & 0xFFFFu;
        float e = s_l[s] + srs[d];
        e = (e > 0.f) ? e : NEG_SLOPE * e;
        float ex = __expf(e);
        int slot = atomicAdd(&cur_s[d], 1);
        sedge[slot] = (unsigned short)s;
        sex[slot]   = ex;
        atomicAdd(&den_s[d], ex);
    }
    __syncthreads();

    // ---- phase 2: 8-lane group per node; no cross-lane ops ----
    const int ch8 = t & 7;       // which 16B chunk (8 bf16 channels) of the row
    const int grp = t >> 3;      // 0..31

    for (int nl = grp; nl < 64; nl += 32) {
        const int n = nbase + nl;
        if (n >= N) continue;
        const int beg = off_s[nl];
        const int end = cur_s[nl];        // == beg + count after scatter
        float4* op = out4 + (size_t)n * 16 + ch8 * 2;

        if (end <= beg) {
            op[0] = make_float4(0.f, 0.f, 0.f, 0.f);
            op[1] = make_float4(0.f, 0.f, 0.f, 0.f);
            continue;
        }

        float a0 = 0.f, a1 = 0.f, a2 = 0.f, a3 = 0.f;
        float a4 = 0.f, a5 = 0.f, a6 = 0.f, a7 = 0.f;

        for (int i = beg; i < end; ++i) {
            int   s  = sedge[i];          // broadcast within group
            float ex = sex[i];            // broadcast within group
            uint4 zv = zb4[(size_t)s * 8 + ch8];
            float f0 = __uint_as_float(zv.x << 16);
            float f1 = __uint_as_float(zv.x & 0xffff0000u);
            float f2 = __uint_as_float(zv.y << 16);
            float f3 = __uint_as_float(zv.y & 0xffff0000u);
            float f4 = __uint_as_float(zv.z << 16);
            float f5 = __uint_as_float(zv.z & 0xffff0000u);
            float f6 = __uint_as_float(zv.w << 16);
            float f7 = __uint_as_float(zv.w & 0xffff0000u);
            a0 += ex * f0; a1 += ex * f1; a2 += ex * f2; a3 += ex * f3;
            a4 += ex * f4; a5 += ex * f5; a6 += ex * f6; a7 += ex * f7;
        }

        float inv = 1.f / den_s[nl];
        op[0] = make_float4(a0 * inv, a1 * inv, a2 * inv, a3 * inv);
        op[1] = make_float4(a4 * inv, a5 * inv, a6 * inv, a7 * inv);
    }
}

extern "C" void kernel_launch(void* const* d_in, const int* in_sizes, int n_in,
                              void* d_out, int out_size, void* d_ws, size_t ws_size,
                              hipStream_t stream)
{
    const float* h     = (const float*)d_in[0];
    const float* Wfc   = (const float*)d_in[1];
    const float* Wattn = (const float*)d_in[2];
    const int*   src   = (const int*)d_in[3];
    const int*   dst   = (const int*)d_in[4];
    const int N = in_sizes[0] / IN_DIM;
    const int E = in_sizes[3];
    const int NBK = (N + 63) / 64;                      // 782 buckets
    const int NP1 = (E + 256 * EPT - 1) / (256 * EPT);  // 196 part1 blocks

    // ws layout: z_bf16[N*64] | s_l[N] | s_r[N] | bucket_cursor[1024] | tmp[NBK*BCAP]
    __hip_bfloat16* zb = (__hip_bfloat16*)d_ws;
    float* s_l     = (float*)(zb + (size_t)N * OUT_DIM);
    float* s_r     = s_l + N;
    int*   bcursor = (int*)(s_r + N);
    unsigned* tmp  = (unsigned*)(bcursor + 1024);

    const int nblk_g = (N + 63) / 64;                   // 782 gemm blocks

    hipMemsetAsync(bcursor, 0, 1024 * sizeof(int), stream);

    k_front<<<NP1 + nblk_g, 256, 0, stream>>>(src, dst, bcursor, tmp, E,
                                              (const float4*)h, (const float4*)Wfc, Wattn,
                                              zb, s_l, s_r, N, NP1);
    k_tail <<<NBK, 256, 0, stream>>>(tmp, bcursor, s_l, s_r,
                                     (const uint4*)zb, (float4*)d_out, N);
}

// Round 10
// 140.571 us; speedup vs baseline: 3.5230x; 1.0168x over previous
//
#include <hip/hip_runtime.h>
#include <hip/hip_bf16.h>
#include <math.h>

#define IN_DIM 128
#define OUT_DIM 64
#define NEG_SLOPE 0.01f
#define BCAP 2048          // slots per 64-node bucket (avg fill ~1023)
#define EPT 16             // edges per thread in part1 (4096 edges/block)

typedef __attribute__((ext_vector_type(8))) short bf8_t;   // 8 bf16 (4 VGPRs)
typedef __attribute__((ext_vector_type(4))) float f4_t;    // MFMA acc

__device__ __forceinline__ bf8_t pack8(float4 a, float4 b) {
    union { bf8_t v; __hip_bfloat162 h[4]; } u;
    u.h[0] = __float22bfloat162_rn(make_float2(a.x, a.y));
    u.h[1] = __float22bfloat162_rn(make_float2(a.z, a.w));
    u.h[2] = __float22bfloat162_rn(make_float2(b.x, b.y));
    u.h[3] = __float22bfloat162_rn(make_float2(b.z, b.w));
    return u.v;
}

// ---- K_front: blocks [0,NP1) = part1 (bin edges), blocks [NP1,..) = MFMA gemm ----
// payload u32 = (bucket<<22) | (src<<6) | (dst&63), bucket = dst>>6 (< 1024).
__global__ __launch_bounds__(256) void k_front(
    const int* __restrict__ src, const int* __restrict__ dst,
    int* __restrict__ bucket_cursor, unsigned* __restrict__ tmp, int E,
    const float4* __restrict__ h4, const float4* __restrict__ W4,
    const float* __restrict__ Wattn,
    __hip_bfloat16* __restrict__ zb, float* __restrict__ s_l, float* __restrict__ s_r,
    int N, int NP1)
{
    __shared__ int cnt[1024];
    __shared__ int cur[1024];

    if (blockIdx.x < NP1) {
        // ================= part1: bin 4096 edges into buckets =================
        const int t = threadIdx.x;
        const int base_e = blockIdx.x * (256 * EPT);

        for (int b = t; b < 1024; b += 256) cnt[b] = 0;
        __syncthreads();

        unsigned pArr[EPT];
        #pragma unroll
        for (int i = 0; i < EPT; i++) {
            int ei = base_e + i * 256 + t;
            if (ei < E) {
                int s = src[ei], d = dst[ei];
                int b = d >> 6;
                pArr[i] = ((unsigned)b << 22) | ((unsigned)s << 6) | (unsigned)(d & 63);
                atomicAdd(&cnt[b], 1);
            } else {
                pArr[i] = 0xFFFFFFFFu;
            }
        }
        __syncthreads();

        for (int b = t; b < 1024; b += 256)
            if (cnt[b] > 0)
                cur[b] = atomicAdd(&bucket_cursor[b], cnt[b]);
        __syncthreads();

        #pragma unroll
        for (int i = 0; i < EPT; i++) {
            unsigned p = pArr[i];
            if (p == 0xFFFFFFFFu) continue;
            int b = p >> 22;
            int slot = atomicAdd(&cur[b], 1);
            if (slot < BCAP)
                tmp[(size_t)b * BCAP + slot] = p;
        }
    } else {
        // ================= gemm: MFMA, 64 nodes per block =================
        const int lane = threadIdx.x & 63;
        const int wv   = threadIdx.x >> 6;
        const int col  = lane & 15, quad = lane >> 4;
        const int n0   = (blockIdx.x - NP1) * 64 + wv * 16;
        if (n0 >= N) return;

        bf8_t bf[4][4];
        #pragma unroll
        for (int ns = 0; ns < 4; ns++) {
            const float4* wrow = W4 + (size_t)(ns * 16 + col) * (IN_DIM / 4);
            #pragma unroll
            for (int kb = 0; kb < 4; kb++) {
                float4 x = wrow[kb * 8 + quad * 2];
                float4 y = wrow[kb * 8 + quad * 2 + 1];
                bf[kb][ns] = pack8(x, y);
            }
        }

        const int  na = n0 + col;
        const bool nv = (na < N);
        const float4* hrow = h4 + (size_t)(nv ? na : 0) * (IN_DIM / 4);
        const float4 zero = make_float4(0.f, 0.f, 0.f, 0.f);

        f4_t acc[4];
        #pragma unroll
        for (int ns = 0; ns < 4; ns++) acc[ns] = (f4_t){0.f, 0.f, 0.f, 0.f};

        #pragma unroll
        for (int kb = 0; kb < 4; kb++) {
            float4 x = nv ? hrow[kb * 8 + quad * 2]     : zero;
            float4 y = nv ? hrow[kb * 8 + quad * 2 + 1] : zero;
            bf8_t a = pack8(x, y);
            #pragma unroll
            for (int ns = 0; ns < 4; ns++)
                acc[ns] = __builtin_amdgcn_mfma_f32_16x16x32_bf16(a, bf[kb][ns], acc[ns], 0, 0, 0);
        }

        float alv[4], arv[4];
        #pragma unroll
        for (int ns = 0; ns < 4; ns++) {
            alv[ns] = Wattn[ns * 16 + col];
            arv[ns] = Wattn[OUT_DIM + ns * 16 + col];
        }
        #pragma unroll
        for (int r = 0; r < 4; r++) {
            const int nn = n0 + quad * 4 + r;
            float pl = acc[0][r] * alv[0] + acc[1][r] * alv[1] + acc[2][r] * alv[2] + acc[3][r] * alv[3];
            float pr = acc[0][r] * arv[0] + acc[1][r] * arv[1] + acc[2][r] * arv[2] + acc[3][r] * arv[3];
            #pragma unroll
            for (int o = 1; o < 16; o <<= 1) {
                pl += __shfl_xor(pl, o, 64);
                pr += __shfl_xor(pr, o, 64);
            }
            if (nn < N) {
                __hip_bfloat16* zr = zb + (size_t)nn * OUT_DIM;
                #pragma unroll
                for (int ns = 0; ns < 4; ns++)
                    zr[ns * 16 + col] = __float2bfloat16(acc[ns][r]);
                if (col == 0) { s_l[nn] = pl; s_r[nn] = pr; }
            }
        }
    }
}

// ---- K_tail: one block per 64-node bucket.
// Phase 1 (two-pass, NO private arrays -> no scratch):
//   pass A: LDS histogram of dst&63; wave-0 shfl scan for offsets.
//   pass B: re-read bucket slab (L2-hot), compute ex, scatter {src,ex} uint2 to LDS.
// Phase 2: one 8-lane group per node; ds_read_b64 broadcast; dsum in registers.
__global__ __launch_bounds__(256) void k_tail(
    const unsigned* __restrict__ tmp, const int* __restrict__ bucket_cnt,
    const float* __restrict__ s_l, const float* __restrict__ s_r,
    const uint4* __restrict__ zb4, float4* __restrict__ out4, int N)
{
    __shared__ uint2 se[BCAP];               // 16 KB: {src, ex bits}
    __shared__ int cnt_s[64], off_s[64], cur_s[64];
    __shared__ float srs[64];

    const int b = blockIdx.x, t = threadIdx.x;
    const int lane = t & 63;
    const int nbase = b * 64;
    int mb = bucket_cnt[b];
    if (mb > BCAP) mb = BCAP;

    if (t < 64) {
        cnt_s[t] = 0;
        int n = nbase + t;
        srs[t] = (n < N) ? s_r[n] : 0.f;
    }
    __syncthreads();

    const unsigned* mybuf = tmp + (size_t)b * BCAP;

    // pass A: histogram
    for (int i = t; i < mb; i += 256)
        atomicAdd(&cnt_s[mybuf[i] & 63u], 1);
    __syncthreads();

    // exclusive scan of cnt_s[64] by wave 0 (shfl only)
    if (t < 64) {
        int c = cnt_s[t];
        int inc = c;
        #pragma unroll
        for (int o = 1; o < 64; o <<= 1) {
            int v = __shfl_up(inc, o, 64);
            if (lane >= o) inc += v;
        }
        off_s[t] = inc - c;
        cur_s[t] = inc - c;
    }
    __syncthreads();

    // pass B: compute ex + scatter
    for (int i = t; i < mb; i += 256) {
        unsigned p = mybuf[i];
        int d = p & 63u;
        int s = (p >> 6) & 0xFFFFu;
        float e = s_l[s] + srs[d];
        e = (e > 0.f) ? e : NEG_SLOPE * e;
        float ex = __expf(e);
        int slot = atomicAdd(&cur_s[d], 1);
        se[slot] = make_uint2((unsigned)s, __float_as_uint(ex));
    }
    __syncthreads();

    // ---- phase 2: 8-lane group per node; no cross-lane ops ----
    const int ch8 = t & 7;       // which 16B chunk (8 bf16 channels) of the row
    const int grp = t >> 3;      // 0..31

    for (int nl = grp; nl < 64; nl += 32) {
        const int n = nbase + nl;
        if (n >= N) continue;
        const int beg = off_s[nl];
        const int end = beg + cnt_s[nl];
        float4* op = out4 + (size_t)n * 16 + ch8 * 2;

        if (end <= beg) {
            op[0] = make_float4(0.f, 0.f, 0.f, 0.f);
            op[1] = make_float4(0.f, 0.f, 0.f, 0.f);
            continue;
        }

        float a0 = 0.f, a1 = 0.f, a2 = 0.f, a3 = 0.f;
        float a4 = 0.f, a5 = 0.f, a6 = 0.f, a7 = 0.f;
        float dsum = 0.f;

        for (int i = beg; i < end; ++i) {
            uint2 q = se[i];              // ds_read_b64, broadcast within group
            float ex = __uint_as_float(q.y);
            dsum += ex;
            uint4 zv = zb4[(size_t)q.x * 8 + ch8];
            float f0 = __uint_as_float(zv.x << 16);
            float f1 = __uint_as_float(zv.x & 0xffff0000u);
            float f2 = __uint_as_float(zv.y << 16);
            float f3 = __uint_as_float(zv.y & 0xffff0000u);
            float f4 = __uint_as_float(zv.z << 16);
            float f5 = __uint_as_float(zv.z & 0xffff0000u);
            float f6 = __uint_as_float(zv.w << 16);
            float f7 = __uint_as_float(zv.w & 0xffff0000u);
            a0 += ex * f0; a1 += ex * f1; a2 += ex * f2; a3 += ex * f3;
            a4 += ex * f4; a5 += ex * f5; a6 += ex * f6; a7 += ex * f7;
        }

        float inv = 1.f / dsum;
        op[0] = make_float4(a0 * inv, a1 * inv, a2 * inv, a3 * inv);
        op[1] = make_float4(a4 * inv, a5 * inv, a6 * inv, a7 * inv);
    }
}

extern "C" void kernel_launch(void* const* d_in, const int* in_sizes, int n_in,
                              void* d_out, int out_size, void* d_ws, size_t ws_size,
                              hipStream_t stream)
{
    const float* h     = (const float*)d_in[0];
    const float* Wfc   = (const float*)d_in[1];
    const float* Wattn = (const float*)d_in[2];
    const int*   src   = (const int*)d_in[3];
    const int*   dst   = (const int*)d_in[4];
    const int N = in_sizes[0] / IN_DIM;
    const int E = in_sizes[3];
    const int NBK = (N + 63) / 64;                      // 782 buckets
    const int NP1 = (E + 256 * EPT - 1) / (256 * EPT);  // 196 part1 blocks

    // ws layout: z_bf16[N*64] | s_l[N] | s_r[N] | bucket_cursor[1024] | tmp[NBK*BCAP]
    __hip_bfloat16* zb = (__hip_bfloat16*)d_ws;
    float* s_l     = (float*)(zb + (size_t)N * OUT_DIM);
    float* s_r     = s_l + N;
    int*   bcursor = (int*)(s_r + N);
    unsigned* tmp  = (unsigned*)(bcursor + 1024);

    const int nblk_g = (N + 63) / 64;                   // 782 gemm blocks

    hipMemsetAsync(bcursor, 0, 1024 * sizeof(int), stream);

    k_front<<<NP1 + nblk_g, 256, 0, stream>>>(src, dst, bcursor, tmp, E,
                                              (const float4*)h, (const float4*)Wfc, Wattn,
                                              zb, s_l, s_r, N, NP1);
    k_tail <<<NBK, 256, 0, stream>>>(tmp, bcursor, s_l, s_r,
                                     (const uint4*)zb, (float4*)d_out, N);
}